// Round 1
// baseline (356.021 us; speedup 1.0000x reference)
//
#include <hip/hip_runtime.h>
#include <math.h>

#define B_ 8
#define L_ 336
#define H_ 192
#define C_ 321
#define K_ 16
#define S_ 8
#define H2_ 97
#define NJ_ 33
#define OUT_ 3201
#define SEQLEN_ 528
#define BC_ (B_ * C_)
#define JD_ 136
#define MIXJ_ 291

static constexpr size_t OFF_SEQ  = 0;
static constexpr size_t OFF_MU   = OFF_SEQ + (size_t)BC_ * SEQLEN_;
static constexpr size_t OFF_STD  = OFF_MU + BC_;
static constexpr size_t OFF_ISTD = OFF_STD + BC_;
static constexpr size_t OFF_P    = OFF_ISTD + BC_;
static constexpr size_t OFF_CF   = OFF_P + (size_t)BC_ * S_;
static constexpr size_t OFF_W2   = OFF_CF + (size_t)BC_ * K_;
static constexpr size_t OFF_WT2  = (OFF_W2 + (size_t)JD_ * OUT_ + 1) & ~(size_t)1;
static constexpr size_t OFF_FILT = OFF_WT2 + (size_t)2 * MIXJ_ * H2_;

#define TWO_PI_F 6.283185307179586f

// ---------------------------------------------------------------------------
// Kernel 1: per-(b,c): instance-norm stats over L, cls logits softmax -> p,
// and corr_feat from r.  One thread per (b,c), coalesced over c.
// ---------------------------------------------------------------------------
__global__ void kStats(const float* __restrict__ x,
                       const float* __restrict__ cls_w,
                       const float* __restrict__ cls_bias,
                       const float* __restrict__ basic_state,
                       const float* __restrict__ r,
                       const float* __restrict__ temperature,
                       float* __restrict__ mu, float* __restrict__ stdv,
                       float* __restrict__ istd, float* __restrict__ p,
                       float* __restrict__ cf) {
  int bc = blockIdx.x * blockDim.x + threadIdx.x;
  if (bc >= BC_) return;
  int b = bc / C_;
  int c = bc - b * C_;
  const float* xb = x + (size_t)b * L_ * C_ + c;

  float sum = 0.f, sumsq = 0.f;
  float acc[S_];
#pragma unroll
  for (int s = 0; s < S_; s++) acc[s] = 0.f;

  for (int l = 0; l < L_; l++) {
    float v = xb[(size_t)l * C_];
    sum += v;
    sumsq = fmaf(v, v, sumsq);
#pragma unroll
    for (int s = 0; s < S_; s++) acc[s] = fmaf(v, cls_w[s * L_ + l], acc[s]);
  }
  float m = sum * (1.f / L_);
  float var = fmaxf(sumsq * (1.f / L_) - m * m, 0.f);
  float sd = sqrtf(var + 1e-8f);
  mu[bc] = m;
  stdv[bc] = sd;
  istd[bc] = 1.f / sd;

  // p = softmax over S of (cls_bias + basic_state + dot)
  float lg[S_];
  float mx = -1e30f;
#pragma unroll
  for (int s = 0; s < S_; s++) {
    lg[s] = acc[s] + cls_bias[s] + basic_state[c * S_ + s];
    mx = fmaxf(mx, lg[s]);
  }
  float den = 0.f;
#pragma unroll
  for (int s = 0; s < S_; s++) {
    float e = expf(lg[s] - mx);
    lg[s] = e;
    den += e;
  }
  float iden = 1.f / den;
#pragma unroll
  for (int s = 0; s < S_; s++) p[(size_t)bc * S_ + s] = lg[s] * iden;

  // corr_feat: softmax([1, |r|]/T)[1:]
  float it = 1.f / temperature[0];
  float a[K_];
  float am = it;  // 1.0 / T
#pragma unroll
  for (int k = 0; k < K_; k++) {
    a[k] = fabsf(r[(size_t)bc * K_ + k]) * it;
    am = fmaxf(am, a[k]);
  }
  float den2 = expf(it - am);
#pragma unroll
  for (int k = 0; k < K_; k++) {
    float e = expf(a[k] - am);
    a[k] = e;
    den2 += e;
  }
  float iden2 = 1.f / den2;
#pragma unroll
  for (int k = 0; k < K_; k++) cf[(size_t)bc * K_ + k] = a[k] * iden2;
}

// ---------------------------------------------------------------------------
// Kernel 2: materialize normalized seq (B, C, 528): [xn | yhn]
// block = one (b,c); coalesced writes along t.
// ---------------------------------------------------------------------------
__global__ void kSeq(const float* __restrict__ x, const float* __restrict__ y_hat,
                     const float* __restrict__ mu, const float* __restrict__ istd,
                     float* __restrict__ seq) {
  int bc = blockIdx.x;
  int b = bc / C_;
  int c = bc - b * C_;
  float m = mu[bc], is = istd[bc];
  float* srow = seq + (size_t)bc * SEQLEN_;
  for (int t = threadIdx.x; t < SEQLEN_; t += blockDim.x) {
    float v = (t < L_) ? x[((size_t)b * L_ + t) * C_ + c]
                       : y_hat[((size_t)b * H_ + (t - L_)) * C_ + c];
    srow[t] = (v - m) * is;
  }
}

// ---------------------------------------------------------------------------
// Kernel 3: pack W2[j][o], j = s*17 + t  (t<16: mh_w[s, t*OUT+o]; t=16: mh_b)
// ---------------------------------------------------------------------------
__global__ void kPackW2(const float* __restrict__ mh_w, const float* __restrict__ mh_b,
                        float* __restrict__ W2) {
  int idx = blockIdx.x * blockDim.x + threadIdx.x;
  if (idx >= JD_ * OUT_) return;
  int j = idx / OUT_;
  int o = idx - j * OUT_;
  int s = j / 17;
  int t = j - s * 17;
  W2[idx] = (t < K_) ? mh_w[(size_t)s * (K_ * OUT_) + (size_t)t * OUT_ + o]
                     : mh_b[(size_t)s * OUT_ + o];
}

// ---------------------------------------------------------------------------
// Kernel 4: pack mix_w transposed + interleaved: wT2[j*97+g] = (wr[g,j], wi[g,j])
// ---------------------------------------------------------------------------
__global__ void kPackMixW(const float* __restrict__ mwr, const float* __restrict__ mwi,
                          float2* __restrict__ wT2) {
  int idx = blockIdx.x * blockDim.x + threadIdx.x;
  if (idx >= MIXJ_ * H2_) return;
  int j = idx / H2_;
  int g = idx - j * H2_;
  wT2[idx] = make_float2(mwr[(size_t)g * MIXJ_ + j], mwi[(size_t)g * MIXJ_ + j]);
}

// ---------------------------------------------------------------------------
// Kernel 5: filt GEMM: filt[row][o] = sum_j u[row][j] * W2[j][o]
// Mtile=16 rows, Ntile=256 o.  u built in LDS from p, cf.
// ---------------------------------------------------------------------------
__launch_bounds__(256)
__global__ void kFilt(const float* __restrict__ p, const float* __restrict__ cf,
                      const float* __restrict__ W2, float* __restrict__ filt) {
  __shared__ __align__(16) float u[16][140];
  int rowBase = blockIdx.y * 16;
  for (int i = threadIdx.x; i < 16 * JD_; i += 256) {
    int m = i / JD_;
    int j = i - m * JD_;
    int row = rowBase + m;
    float v = 0.f;
    if (row < BC_) {
      int s = j / 17;
      int t = j - s * 17;
      float ps = p[(size_t)row * S_ + s];
      v = (t < K_) ? ps * cf[(size_t)row * K_ + t] : ps;
    }
    u[m][j] = v;
  }
  __syncthreads();

  int o = blockIdx.x * 256 + threadIdx.x;
  if (o >= OUT_) return;
  float accv[16];
#pragma unroll
  for (int m = 0; m < 16; m++) accv[m] = 0.f;

  for (int jq = 0; jq < JD_ / 4; jq++) {
    int j = jq * 4;
    float w0 = W2[(size_t)(j + 0) * OUT_ + o];
    float w1 = W2[(size_t)(j + 1) * OUT_ + o];
    float w2 = W2[(size_t)(j + 2) * OUT_ + o];
    float w3 = W2[(size_t)(j + 3) * OUT_ + o];
#pragma unroll
    for (int m = 0; m < 16; m++) {
      float4 uv = *reinterpret_cast<const float4*>(&u[m][j]);
      accv[m] = fmaf(uv.x, w0, fmaf(uv.y, w1, fmaf(uv.z, w2, fmaf(uv.w, w3, accv[m]))));
    }
  }
#pragma unroll
  for (int m = 0; m < 16; m++) {
    int row = rowBase + m;
    if (row < BC_) filt[(size_t)row * OUT_ + o] = accv[m];
  }
}

// ---------------------------------------------------------------------------
// Kernel 6: main — per (b,c): gather rows, 17x DFT(192->97), filt combine,
// complex mix matmul, irfft, epilogue.
// ---------------------------------------------------------------------------
__launch_bounds__(128)
__global__ void kMain(const float* __restrict__ seq, const float* __restrict__ mu,
                      const float* __restrict__ stdv, const float* __restrict__ filt,
                      const int* __restrict__ lead, const int* __restrict__ shiftv,
                      const float* __restrict__ r, const float2* __restrict__ wT2,
                      const float* __restrict__ mbr, const float* __restrict__ mbi,
                      float* __restrict__ out) {
  __shared__ __align__(16) float rows[17][192];
  __shared__ float mixr[MIXJ_];
  __shared__ float mixi[MIXJ_];
  __shared__ float zr_s[H2_];
  __shared__ float zi_s[H2_];

  int bc = blockIdx.x;
  int b = bc / C_;
  int c = bc - b * C_;
  int tid = threadIdx.x;

  // phase 1: gather 16 leader windows (+sign) and own yhn row into LDS
#pragma unroll 1
  for (int k = 0; k < K_; k++) {
    int ld = lead[(size_t)bc * K_ + k];
    int sh = shiftv[(size_t)bc * K_ + k];
    float rv = r[(size_t)bc * K_ + k];
    float sg = (rv > 0.f) ? 1.f : ((rv < 0.f) ? -1.f : 0.f);
    const float* src = seq + ((size_t)b * C_ + ld) * SEQLEN_ + (L_ - sh);
    for (int h = tid; h < H_; h += 128) rows[k][h] = src[h] * sg;
  }
  {
    const float* src = seq + (size_t)bc * SEQLEN_ + L_;
    for (int h = tid; h < H_; h += 128) rows[16][h] = src[h];
  }
  __syncthreads();

  int f = tid;
  float aR[17], aI[17];
  if (f < H2_) {
    // phase 2: DFT via incremental rotation, h unrolled by 4
#pragma unroll
    for (int k = 0; k < 17; k++) { aR[k] = 0.f; aI[k] = 0.f; }
    float ang = -(TWO_PI_F / 192.f) * (float)f;
    float cc1, ss1, cc2, ss2, cc3, ss3, cc4, ss4;
    sincosf(ang, &ss1, &cc1);
    sincosf(2.f * ang, &ss2, &cc2);
    sincosf(3.f * ang, &ss3, &cc3);
    sincosf(4.f * ang, &ss4, &cc4);
    float cr = 1.f, ci = 0.f;
    for (int h = 0; h < H_; h += 4) {
      float c0 = cr, s0 = ci;
      float c1 = cr * cc1 - ci * ss1, s1 = cr * ss1 + ci * cc1;
      float c2 = cr * cc2 - ci * ss2, s2 = cr * ss2 + ci * cc2;
      float c3 = cr * cc3 - ci * ss3, s3 = cr * ss3 + ci * cc3;
      float nr = cr * cc4 - ci * ss4, ni = cr * ss4 + ci * cc4;
      cr = nr; ci = ni;
#pragma unroll
      for (int k = 0; k < 17; k++) {
        float4 v = *reinterpret_cast<const float4*>(&rows[k][h]);
        aR[k] = fmaf(v.x, c0, fmaf(v.y, c1, fmaf(v.z, c2, fmaf(v.w, c3, aR[k]))));
        aI[k] = fmaf(v.x, s0, fmaf(v.y, s1, fmaf(v.z, s2, fmaf(v.w, s3, aI[k]))));
      }
    }

    // phase 3: combine with filt -> mix_in
    const float* fb = filt + (size_t)bc * OUT_ + f;
    float yfR = aR[16], yfI = aI[16];
    float S1r = 0.f, S1i = 0.f, S2r = 0.f, S2i = 0.f, sg2 = 0.f;
#pragma unroll
    for (int k = 0; k < K_; k++) {
      float g1 = fb[k * H2_];
      float g2 = fb[(K_ + k) * H2_];
      float g12 = g1 * g2;
      S1r = fmaf(aR[k], g1, S1r);
      S1i = fmaf(aI[k], g1, S1i);
      S2r = fmaf(aR[k], g12, S2r);
      S2i = fmaf(aI[k], g12, S2i);
      sg2 += g2;
    }
    S2r = fmaf(-yfR, sg2, S2r);
    S2i = fmaf(-yfI, sg2, S2i);
    float g3 = fb[32 * H2_];
    mixr[f] = S1r;          mixi[f] = S1i;
    mixr[H2_ + f] = S2r;    mixi[H2_ + f] = S2i;
    mixr[2 * H2_ + f] = yfR * g3;
    mixi[2 * H2_ + f] = yfI * g3;
  }
  __syncthreads();

  // phase 4: z[g] = mix_b[g] + sum_j mix[j] * mix_w[g, j]  (complex)
  if (f < H2_) {
    float zr = mbr[f], zi = mbi[f];
    for (int j = 0; j < MIXJ_; j++) {
      float2 wv = wT2[(size_t)j * H2_ + f];
      float mr = mixr[j], mi2 = mixi[j];
      zr = fmaf(mr, wv.x, fmaf(-mi2, wv.y, zr));
      zi = fmaf(mr, wv.y, fmaf(mi2, wv.x, zi));
    }
    zr_s[f] = zr;
    zi_s[f] = zi;
  }
  __syncthreads();

  // phase 5: irfft + epilogue + transposed store
  float m = mu[bc], sd = stdv[bc];
  for (int h = tid; h < H_; h += 128) {
    float ang = (TWO_PI_F / 192.f) * (float)h;
    float cs, sn;
    sincosf(ang, &sn, &cs);
    float acc = 0.5f * zr_s[0] + ((h & 1) ? -0.5f : 0.5f) * zr_s[96];
    float cv = 1.f, sv = 0.f;
    for (int fq = 1; fq < 96; fq++) {
      float nc = cv * cs - sv * sn;
      float ns = cv * sn + sv * cs;
      cv = nc; sv = ns;
      acc = fmaf(zr_s[fq], cv, fmaf(-zi_s[fq], sv, acc));
    }
    float yv = acc * (2.f / 192.f);
    float yhnv = rows[16][h];
    out[((size_t)b * H_ + h) * C_ + c] = fmaf(yhnv + yv, sd, m);
  }
}

// ---------------------------------------------------------------------------
extern "C" void kernel_launch(void* const* d_in, const int* in_sizes, int n_in,
                              void* d_out, int out_size, void* d_ws, size_t ws_size,
                              hipStream_t stream) {
  const float* x           = (const float*)d_in[0];
  const float* y_hat       = (const float*)d_in[1];
  const int*   lead        = (const int*)d_in[2];
  const int*   shiftv      = (const int*)d_in[3];
  const float* r           = (const float*)d_in[4];
  const float* temperature = (const float*)d_in[5];
  const float* cls_w       = (const float*)d_in[6];
  const float* cls_bias    = (const float*)d_in[7];
  const float* basic_state = (const float*)d_in[8];
  const float* mh_w        = (const float*)d_in[9];
  const float* mh_b        = (const float*)d_in[10];
  const float* mwr         = (const float*)d_in[11];
  const float* mwi         = (const float*)d_in[12];
  const float* mbr         = (const float*)d_in[13];
  const float* mbi         = (const float*)d_in[14];
  float* out = (float*)d_out;
  float* ws  = (float*)d_ws;

  kStats<<<(BC_ + 255) / 256, 256, 0, stream>>>(
      x, cls_w, cls_bias, basic_state, r, temperature,
      ws + OFF_MU, ws + OFF_STD, ws + OFF_ISTD, ws + OFF_P, ws + OFF_CF);

  kSeq<<<BC_, 128, 0, stream>>>(x, y_hat, ws + OFF_MU, ws + OFF_ISTD, ws + OFF_SEQ);

  kPackW2<<<(JD_ * OUT_ + 255) / 256, 256, 0, stream>>>(mh_w, mh_b, ws + OFF_W2);

  kPackMixW<<<(MIXJ_ * H2_ + 255) / 256, 256, 0, stream>>>(
      mwr, mwi, (float2*)(ws + OFF_WT2));

  dim3 gF((OUT_ + 255) / 256, (BC_ + 15) / 16);
  kFilt<<<gF, 256, 0, stream>>>(ws + OFF_P, ws + OFF_CF, ws + OFF_W2, ws + OFF_FILT);

  kMain<<<BC_, 128, 0, stream>>>(ws + OFF_SEQ, ws + OFF_MU, ws + OFF_STD,
                                 ws + OFF_FILT, lead, shiftv, r,
                                 (const float2*)(ws + OFF_WT2), mbr, mbi, out);
}